// Round 4
// baseline (133.940 us; speedup 1.0000x reference)
//
#include <hip/hip_runtime.h>

#define BB 2
#define CIN 64
#define CQ 32
#define DD 8
#define HH 16
#define WWW 16
#define NN 2048   // D*H*W
#define NHW 256   // H*W
#define COUT 64

#define XPLANE 324          // 18*18 padded plane
#define CI_QKV 8            // ci staged per barrier phase (qkv conv)
#define CI_OUT 8            // ci per block (out conv) -- single stage

#define NPART 16            // softmax partials (mz nchunks == att mchunks)
#define LOG2E 1.44269504088896340736f

// ---- init: qkv bufs <- bias ; out <- x + bias (conv kernels atomically accumulate) ----
__global__ __launch_bounds__(256) void init_kernel(
    const float* __restrict__ bk, const float* __restrict__ bq, const float* __restrict__ bv,
    const float* __restrict__ ba, const float* __restrict__ x,
    float* __restrict__ kout, float* __restrict__ qout, float* __restrict__ vout,
    float* __restrict__ out)
{
    int i = blockIdx.x * 256 + threadIdx.x;   // 0 .. 393215
    if (i < BB * CQ * NN) {
        int co = (i >> 11) & 31;
        kout[i] = bk[co];
        qout[i] = bq[co];
        vout[i] = bv[co];
    } else {
        int j = i - BB * CQ * NN;             // 0 .. 262143
        int co = (j >> 11) & 63;
        out[j] = x[j] + ba[co];
    }
}

// ---- fused k,q,v conv: grid 2b*8d*16co2*4cisplit = 1024 blocks, 256 threads ----
__global__ __launch_bounds__(256, 4) void conv_qkv_kernel(
    const float* __restrict__ x,
    const float* __restrict__ wk, const float* __restrict__ wq, const float* __restrict__ wv,
    float* __restrict__ kout, float* __restrict__ qout, float* __restrict__ vout)
{
    int bid   = blockIdx.x;
    int split = bid & 3;
    int co2   = (bid >> 2) & 15;
    int d     = (bid >> 6) & 7;
    int b     = bid >> 9;
    int co0   = co2 << 1;
    int ci0   = split << 4;    // 16 ci per split

    __shared__ float xl[CI_QKV * 3 * XPLANE];   // 31104 B

    int tid = threadIdx.x;
    int h  = tid >> 4;
    int w  = tid & 15;
    int wr = (h + 1) * 18 + (w + 1);   // interior store offset
    int rb = h * 18 + w;               // read base

    const float* xb = x + ((size_t)b * CIN + ci0) * NN;

    float r[CI_QKV * 3];
    #pragma unroll
    for (int kd = 0; kd < 3; ++kd) {
        int dd = d + kd - 1;
        bool ok = (dd >= 0) && (dd < DD);
        #pragma unroll
        for (int cc = 0; cc < CI_QKV; ++cc)
            r[cc * 3 + kd] = ok ? xb[(size_t)cc * NN + dd * NHW + tid] : 0.f;
    }
    for (int i = tid; i < CI_QKV * 3 * XPLANE; i += 256) xl[i] = 0.f;
    __syncthreads();
    #pragma unroll
    for (int j = 0; j < CI_QKV * 3; ++j)
        xl[j * XPLANE + wr] = r[j];

    float a0 = 0.f, a1 = 0.f, a2 = 0.f, a3 = 0.f, a4 = 0.f, a5 = 0.f;

    #pragma unroll 1
    for (int it = 0; it < 16; it += CI_QKV) {
        __syncthreads();
        if (it + CI_QKV < 16) {
            #pragma unroll
            for (int kd = 0; kd < 3; ++kd) {
                int dd = d + kd - 1;
                bool ok = (dd >= 0) && (dd < DD);
                #pragma unroll
                for (int cc = 0; cc < CI_QKV; ++cc)
                    r[cc * 3 + kd] = ok ?
                        xb[(size_t)(it + CI_QKV + cc) * NN + dd * NHW + tid] : 0.f;
            }
        }

        for (int cc = 0; cc < CI_QKV; ++cc) {
            int ci = ci0 + it + cc;
            const float* wk0 = wk + ((size_t)co0 * CIN + ci) * 27;
            const float* wk1 = wk0 + (size_t)CIN * 27;
            const float* wq0 = wq + ((size_t)co0 * CIN + ci) * 27;
            const float* wq1 = wq0 + (size_t)CIN * 27;
            const float* wv0 = wv + ((size_t)co0 * CIN + ci) * 27;
            const float* wv1 = wv0 + (size_t)CIN * 27;
            const float* xp  = xl + cc * 3 * XPLANE + rb;
            #pragma unroll
            for (int kd = 0; kd < 3; ++kd) {
                int dd = d + kd - 1;
                if (dd < 0 || dd >= DD) continue;   // block-uniform
                #pragma unroll
                for (int kh = 0; kh < 3; ++kh) {
                    #pragma unroll
                    for (int kw = 0; kw < 3; ++kw) {
                        float xv = xp[kd * XPLANE + kh * 18 + kw];
                        int t = kd * 9 + kh * 3 + kw;
                        a0 = fmaf(xv, wk0[t], a0);
                        a1 = fmaf(xv, wk1[t], a1);
                        a2 = fmaf(xv, wq0[t], a2);
                        a3 = fmaf(xv, wq1[t], a3);
                        a4 = fmaf(xv, wv0[t], a4);
                        a5 = fmaf(xv, wv1[t], a5);
                    }
                }
            }
        }

        __syncthreads();
        if (it + CI_QKV < 16) {
            #pragma unroll
            for (int j = 0; j < CI_QKV * 3; ++j)
                xl[j * XPLANE + wr] = r[j];
        }
    }

    size_t o0 = ((size_t)b * CQ + co0) * NN + d * NHW + tid;
    unsafeAtomicAdd(&kout[o0],      a0);
    unsafeAtomicAdd(&kout[o0 + NN], a1);
    unsafeAtomicAdd(&qout[o0],      a2);
    unsafeAtomicAdd(&qout[o0 + NN], a3);
    unsafeAtomicAdd(&vout[o0],      a4);
    unsafeAtomicAdd(&vout[o0 + NN], a5);
}

// ---- partial softmax column stats: grid 32c*2mtile*16nchunk = 1024 blocks ----
// Register-blocked: each thread owns 4 m (k in regs), streams a 128-n q chunk
// from LDS with wave-uniform broadcast reads (conflict-free). q pre-scaled by
// log2e so exp is native exp2. pmax/psum layout: [c][nchunk][m] (32*16*2048)
__global__ __launch_bounds__(256) void mz_partial_kernel(
    const float* __restrict__ kbuf, const float* __restrict__ qbuf,
    float* __restrict__ pmax, float* __restrict__ psum)
{
    int bid = blockIdx.x;
    int nchunk = bid & 15;
    int mtile  = (bid >> 4) & 1;
    int c      = bid >> 5;

    __shared__ float q0l[128], q1l[128];
    int tid = threadIdx.x;
    int n0 = nchunk * 128;
    if (tid < 32) {
        float4 v = ((const float4*)(qbuf + (size_t)c * NN + n0))[tid];
        v.x *= LOG2E; v.y *= LOG2E; v.z *= LOG2E; v.w *= LOG2E;
        ((float4*)q0l)[tid] = v;
    } else if (tid < 64) {
        float4 v = ((const float4*)(qbuf + (size_t)(CQ + c) * NN + n0))[tid - 32];
        v.x *= LOG2E; v.y *= LOG2E; v.z *= LOG2E; v.w *= LOG2E;
        ((float4*)q1l)[tid - 32] = v;
    }
    __syncthreads();

    int m = mtile * 1024 + tid * 4;
    float4 k0 = *(const float4*)(kbuf + (size_t)c * NN + m);
    float4 k1 = *(const float4*)(kbuf + (size_t)(CQ + c) * NN + m);

    const float4* q0v = (const float4*)q0l;
    const float4* q1v = (const float4*)q1l;

    float mx0 = -1e30f, mx1 = -1e30f, mx2 = -1e30f, mx3 = -1e30f;
    #pragma unroll 4
    for (int i = 0; i < 32; ++i) {
        float4 a = q0v[i], b = q1v[i];
        #define MZP1(KX,K1X,MX) { \
            float s0 = fmaf(KX, a.x, K1X * b.x); \
            float s1 = fmaf(KX, a.y, K1X * b.y); \
            float s2 = fmaf(KX, a.z, K1X * b.z); \
            float s3 = fmaf(KX, a.w, K1X * b.w); \
            MX = fmaxf(MX, fmaxf(fmaxf(s0, s1), fmaxf(s2, s3))); }
        MZP1(k0.x, k1.x, mx0)
        MZP1(k0.y, k1.y, mx1)
        MZP1(k0.z, k1.z, mx2)
        MZP1(k0.w, k1.w, mx3)
        #undef MZP1
    }

    float nm0 = -mx0, nm1 = -mx1, nm2 = -mx2, nm3 = -mx3;
    float z0 = 0.f, z1 = 0.f, z2 = 0.f, z3 = 0.f;
    #pragma unroll 4
    for (int i = 0; i < 32; ++i) {
        float4 a = q0v[i], b = q1v[i];
        #define MZP2(KX,K1X,NM,Z) { \
            Z += exp2f(fmaf(KX, a.x, fmaf(K1X, b.x, NM))) \
               + exp2f(fmaf(KX, a.y, fmaf(K1X, b.y, NM))) \
               + exp2f(fmaf(KX, a.z, fmaf(K1X, b.z, NM))) \
               + exp2f(fmaf(KX, a.w, fmaf(K1X, b.w, NM))); }
        MZP2(k0.x, k1.x, nm0, z0)
        MZP2(k0.y, k1.y, nm1, z1)
        MZP2(k0.z, k1.z, nm2, z2)
        MZP2(k0.w, k1.w, nm3, z3)
        #undef MZP2
    }
    size_t o = ((size_t)c * NPART + nchunk) * NN + m;
    float4 rm; rm.x = mx0; rm.y = mx1; rm.z = mx2; rm.w = mx3;
    float4 rz; rz.x = z0;  rz.y = z1;  rz.z = z2;  rz.w = z3;
    *(float4*)(pmax + o) = rm;
    *(float4*)(psum + o) = rz;
}

// ---- attention apply partial: grid 32c*2ntile*16mchunk = 1024 blocks ----
// Register-blocked: each thread owns 4 n (pre-scaled q in regs); 128-m chunk
// of k/vz/negM staged in LDS, each read feeds 4 n. parts: 16 x [c][n][b]
__global__ __launch_bounds__(256) void att_partial_kernel(
    const float* __restrict__ kbuf, const float* __restrict__ qbuf,
    const float* __restrict__ vbuf,
    const float* __restrict__ pmax, const float* __restrict__ psum,
    float* __restrict__ parts)
{
    int bid = blockIdx.x;
    int mchunk = bid & 15;
    int ntile  = (bid >> 4) & 1;
    int c      = bid >> 5;

    __shared__ float k0l[128], k1l[128], vz0l[128], vz1l[128], nMl[128];
    int tid = threadIdx.x;
    if (tid < 128) {
        int m = mchunk * 128 + tid;
        float pj[NPART];
        float M = -1e30f;
        #pragma unroll
        for (int j = 0; j < NPART; ++j) {
            pj[j] = pmax[((size_t)c * NPART + j) * NN + m];
            M = fmaxf(M, pj[j]);
        }
        float z = 0.f;
        #pragma unroll
        for (int j = 0; j < NPART; ++j)
            z += psum[((size_t)c * NPART + j) * NN + m] * exp2f(pj[j] - M);
        float rz = 1.f / z;   // z >= 1 always
        k0l[tid]  = kbuf[(size_t)c * NN + m];
        k1l[tid]  = kbuf[(size_t)(CQ + c) * NN + m];
        vz0l[tid] = vbuf[(size_t)c * NN + m] * rz;
        vz1l[tid] = vbuf[(size_t)(CQ + c) * NN + m] * rz;
        nMl[tid]  = -M;
    }
    __syncthreads();

    int n = ntile * 1024 + tid * 4;
    float4 q0 = *(const float4*)(qbuf + (size_t)c * NN + n);
    float4 q1 = *(const float4*)(qbuf + (size_t)(CQ + c) * NN + n);
    q0.x *= LOG2E; q0.y *= LOG2E; q0.z *= LOG2E; q0.w *= LOG2E;
    q1.x *= LOG2E; q1.y *= LOG2E; q1.z *= LOG2E; q1.w *= LOG2E;

    const float4* k0v = (const float4*)k0l;
    const float4* k1v = (const float4*)k1l;
    const float4* v0v = (const float4*)vz0l;
    const float4* v1v = (const float4*)vz1l;
    const float4* nMv = (const float4*)nMl;

    float a00 = 0.f, a01 = 0.f, a02 = 0.f, a03 = 0.f;   // b = 0, n+0..3
    float a10 = 0.f, a11 = 0.f, a12 = 0.f, a13 = 0.f;   // b = 1

    #pragma unroll 2
    for (int i = 0; i < 32; ++i) {
        float4 kk0 = k0v[i], kk1 = k1v[i], w0 = v0v[i], w1 = v1v[i], nm = nMv[i];
        #define ATTS(KX,K1X,W0X,W1X,NMX) { \
            float e0 = exp2f(fmaf(q0.x, KX, fmaf(q1.x, K1X, NMX))); \
            float e1 = exp2f(fmaf(q0.y, KX, fmaf(q1.y, K1X, NMX))); \
            float e2 = exp2f(fmaf(q0.z, KX, fmaf(q1.z, K1X, NMX))); \
            float e3 = exp2f(fmaf(q0.w, KX, fmaf(q1.w, K1X, NMX))); \
            a00 = fmaf(e0, W0X, a00); a10 = fmaf(e0, W1X, a10); \
            a01 = fmaf(e1, W0X, a01); a11 = fmaf(e1, W1X, a11); \
            a02 = fmaf(e2, W0X, a02); a12 = fmaf(e2, W1X, a12); \
            a03 = fmaf(e3, W0X, a03); a13 = fmaf(e3, W1X, a13); }
        ATTS(kk0.x, kk1.x, w0.x, w1.x, nm.x)
        ATTS(kk0.y, kk1.y, w0.y, w1.y, nm.y)
        ATTS(kk0.z, kk1.z, w0.z, w1.z, nm.z)
        ATTS(kk0.w, kk1.w, w0.w, w1.w, nm.w)
        #undef ATTS
    }

    float* dst = parts + (size_t)mchunk * (CQ * NN * BB);
    size_t base = ((size_t)c * NN + n) * BB;
    float4 r0; r0.x = a00; r0.y = a10; r0.z = a01; r0.w = a11;
    float4 r1; r1.x = a02; r1.y = a12; r1.z = a03; r1.w = a13;
    *(float4*)(dst + base)     = r0;
    *(float4*)(dst + base + 4) = r1;
}

// ---- sum 16 partials -> ybuf: grid 128 blocks ----
__global__ __launch_bounds__(256) void combine_kernel(
    const float* __restrict__ parts, float* __restrict__ ybuf)
{
    int i = blockIdx.x * 256 + threadIdx.x;   // float4 index, 32768 total
    float4 s = ((const float4*)parts)[i];
    #pragma unroll
    for (int j = 1; j < NPART; ++j) {
        float4 p = ((const float4*)(parts + (size_t)j * (CQ * NN * BB)))[i];
        s.x += p.x; s.y += p.y; s.z += p.z; s.w += p.w;
    }
    ((float4*)ybuf)[i] = s;
}

// ---- final conv (32->64): grid 2b*8d*16cog*4cisplit = 1024 blocks ----
__global__ __launch_bounds__(256, 4) void conv_out_kernel(
    const float* __restrict__ ybuf,
    const float* __restrict__ wa,
    float* __restrict__ out)
{
    int bid   = blockIdx.x;
    int split = bid & 3;
    int cog   = (bid >> 2) & 15;
    int d     = (bid >> 6) & 7;
    int b     = bid >> 9;
    int co0   = cog << 2;
    int ci0   = split << 3;   // 8 ci per split

    __shared__ float yl[CI_OUT * 3 * XPLANE];   // 31104 B

    int tid = threadIdx.x;
    int h  = tid >> 4;
    int w  = tid & 15;
    int wr = (h + 1) * 18 + (w + 1);
    int rb = h * 18 + w;

    const float* yb = ybuf + ((size_t)b * CQ + ci0) * NN;

    float r[CI_OUT * 3];
    #pragma unroll
    for (int kd = 0; kd < 3; ++kd) {
        int dd = d + kd - 1;
        bool ok = (dd >= 0) && (dd < DD);
        #pragma unroll
        for (int cc = 0; cc < CI_OUT; ++cc)
            r[cc * 3 + kd] = ok ? yb[(size_t)cc * NN + dd * NHW + tid] : 0.f;
    }
    for (int i = tid; i < CI_OUT * 3 * XPLANE; i += 256) yl[i] = 0.f;
    __syncthreads();
    #pragma unroll
    for (int j = 0; j < CI_OUT * 3; ++j)
        yl[j * XPLANE + wr] = r[j];
    __syncthreads();

    float a0 = 0.f, a1 = 0.f, a2 = 0.f, a3 = 0.f;

    for (int cc = 0; cc < CI_OUT; ++cc) {
        int ci = ci0 + cc;
        const float* w0 = wa + ((size_t)(co0 + 0) * CQ + ci) * 27;
        const float* w1 = wa + ((size_t)(co0 + 1) * CQ + ci) * 27;
        const float* w2 = wa + ((size_t)(co0 + 2) * CQ + ci) * 27;
        const float* w3 = wa + ((size_t)(co0 + 3) * CQ + ci) * 27;
        const float* yp = yl + cc * 3 * XPLANE + rb;
        #pragma unroll
        for (int kd = 0; kd < 3; ++kd) {
            int dd = d + kd - 1;
            if (dd < 0 || dd >= DD) continue;   // block-uniform
            #pragma unroll
            for (int kh = 0; kh < 3; ++kh) {
                #pragma unroll
                for (int kw = 0; kw < 3; ++kw) {
                    float yv = yp[kd * XPLANE + kh * 18 + kw];
                    int t = kd * 9 + kh * 3 + kw;
                    a0 = fmaf(yv, w0[t], a0);
                    a1 = fmaf(yv, w1[t], a1);
                    a2 = fmaf(yv, w2[t], a2);
                    a3 = fmaf(yv, w3[t], a3);
                }
            }
        }
    }

    size_t o = ((size_t)b * COUT + co0) * NN + d * NHW + tid;
    unsafeAtomicAdd(&out[o],          a0);
    unsafeAtomicAdd(&out[o + NN],     a1);
    unsafeAtomicAdd(&out[o + 2 * NN], a2);
    unsafeAtomicAdd(&out[o + 3 * NN], a3);
}

extern "C" void kernel_launch(void* const* d_in, const int* in_sizes, int n_in,
                              void* d_out, int out_size, void* d_ws, size_t ws_size,
                              hipStream_t stream) {
    const float* x  = (const float*)d_in[0];
    const float* wk = (const float*)d_in[1];
    const float* bk = (const float*)d_in[2];
    const float* wq = (const float*)d_in[3];
    const float* bq = (const float*)d_in[4];
    const float* wv = (const float*)d_in[5];
    const float* bv = (const float*)d_in[6];
    const float* wa = (const float*)d_in[7];
    const float* ba = (const float*)d_in[8];
    float* out = (float*)d_out;

    float* ws   = (float*)d_ws;
    float* kbuf = ws;                        // [2][32][2048]         131072
    float* qbuf = kbuf + BB * CQ * NN;       // [2][32][2048]         131072
    float* vbuf = qbuf + BB * CQ * NN;       // [2][32][2048]         131072
    float* pmax = vbuf + BB * CQ * NN;       // [32][16][2048]        1048576
    float* psum = pmax + CQ * NPART * NN;    // [32][16][2048]        1048576
    float* parts = psum + CQ * NPART * NN;   // 16 x [32][2048][2]    2097152
    float* ybuf = kbuf;                      // alias: kbuf dead after att

    init_kernel<<<1536, 256, 0, stream>>>(bk, bq, bv, ba, x, kbuf, qbuf, vbuf, out);
    conv_qkv_kernel<<<1024, 256, 0, stream>>>(x, wk, wq, wv, kbuf, qbuf, vbuf);
    mz_partial_kernel<<<1024, 256, 0, stream>>>(kbuf, qbuf, pmax, psum);
    att_partial_kernel<<<1024, 256, 0, stream>>>(kbuf, qbuf, vbuf, pmax, psum, parts);
    combine_kernel<<<128, 256, 0, stream>>>(parts, ybuf);
    conv_out_kernel<<<1024, 256, 0, stream>>>(ybuf, wa, out);
}

// Round 5
// 111.949 us; speedup vs baseline: 1.1964x; 1.1964x over previous
//
#include <hip/hip_runtime.h>

#define BB 2
#define CIN 64
#define CQ 32
#define DD 8
#define HH 16
#define WWW 16
#define NN 2048   // D*H*W
#define NHW 256   // H*W
#define COUT 64

#define XPLANE 324          // 18*18 padded plane
#define CI_OUT 8            // ci per block (out conv) -- single stage

#define NPART 8             // softmax partials (mz nchunks == att mchunks)
#define LOG2E 1.44269504088896340736f

__device__ __forceinline__ float fast_exp2(float x) {
#if __has_builtin(__builtin_amdgcn_exp2f)
    return __builtin_amdgcn_exp2f(x);    // single v_exp_f32
#else
    return exp2f(x);
#endif
}

// ---- init: qkv bufs <- bias ; out <- x + bias (conv kernels atomically accumulate) ----
__global__ __launch_bounds__(256) void init_kernel(
    const float* __restrict__ bk, const float* __restrict__ bq, const float* __restrict__ bv,
    const float* __restrict__ ba, const float* __restrict__ x,
    float* __restrict__ kout, float* __restrict__ qout, float* __restrict__ vout,
    float* __restrict__ out)
{
    int i = blockIdx.x * 256 + threadIdx.x;   // 0 .. 393215
    if (i < BB * CQ * NN) {
        int co = (i >> 11) & 31;
        kout[i] = bk[co];
        qout[i] = bq[co];
        vout[i] = bv[co];
    } else {
        int j = i - BB * CQ * NN;             // 0 .. 262143
        int co = (j >> 11) & 63;
        out[j] = x[j] + ba[co];
    }
}

// ---- fused k,q,v conv: grid 2b*4dpair*16co2*8cisplit = 1024 blocks, 256 threads ----
// Each thread computes output planes d0 and d0+1 (d-pair blocking: each weight
// word feeds 2 FMAs). Weights preloaded to LDS once per block (in-order ds_read,
// no SMEM->lgkmcnt(0) drains). x staged as 4 dd-planes per ci, zero-halo'd 18x18.
__global__ __launch_bounds__(256, 4) void conv_qkv_kernel(
    const float* __restrict__ x,
    const float* __restrict__ wk, const float* __restrict__ wq, const float* __restrict__ wv,
    float* __restrict__ kout, float* __restrict__ qout, float* __restrict__ vout)
{
    int bid   = blockIdx.x;
    int split = bid & 7;          // 8 ci per split
    int co2   = (bid >> 3) & 15;
    int dp    = (bid >> 7) & 3;
    int b     = bid >> 9;
    int co0   = co2 << 1;
    int ci0   = split << 3;
    int d0    = dp << 1;          // output planes d0, d0+1

    __shared__ float xl[4 * 4 * XPLANE];     // [cc][plane p: dd=d0-1+p][324]  20736 B
    __shared__ float wlds[6 * 8 * 27];       // [set][ci_local][27]            5184 B

    int tid = threadIdx.x;
    int h  = tid >> 4;
    int w  = tid & 15;
    int wr = (h + 1) * 18 + (w + 1);
    int rb = h * 18 + w;

    // ---- one-time weight preload (6 segments of 8*27=216 consecutive floats) ----
    {
        const float* ws0 = wk + ((size_t)(co0    ) * CIN + ci0) * 27;
        const float* ws1 = wk + ((size_t)(co0 + 1) * CIN + ci0) * 27;
        const float* ws2 = wq + ((size_t)(co0    ) * CIN + ci0) * 27;
        const float* ws3 = wq + ((size_t)(co0 + 1) * CIN + ci0) * 27;
        const float* ws4 = wv + ((size_t)(co0    ) * CIN + ci0) * 27;
        const float* ws5 = wv + ((size_t)(co0 + 1) * CIN + ci0) * 27;
        if (tid < 216) {
            wlds[0 * 216 + tid] = ws0[tid];
            wlds[1 * 216 + tid] = ws1[tid];
            wlds[2 * 216 + tid] = ws2[tid];
            wlds[3 * 216 + tid] = ws3[tid];
            wlds[4 * 216 + tid] = ws4[tid];
            wlds[5 * 216 + tid] = ws5[tid];
        }
    }

    const float* xb = x + ((size_t)b * CIN + ci0) * NN;

    // prefetch first 4 ci (4 planes each)
    float r[16];
    #pragma unroll
    for (int p = 0; p < 4; ++p) {
        int dd = d0 - 1 + p;
        bool ok = (dd >= 0) && (dd < DD);
        #pragma unroll
        for (int cc = 0; cc < 4; ++cc)
            r[cc * 4 + p] = ok ? xb[(size_t)cc * NN + dd * NHW + tid] : 0.f;
    }
    for (int i = tid; i < 16 * XPLANE; i += 256) xl[i] = 0.f;
    __syncthreads();
    #pragma unroll
    for (int j = 0; j < 16; ++j)
        xl[j * XPLANE + wr] = r[j];

    // accumulators: s0..s5 = {k co0, k co1, q co0, q co1, v co0, v co1}; a=d0, b=d0+1
    float s0a = 0.f, s0b = 0.f, s1a = 0.f, s1b = 0.f, s2a = 0.f, s2b = 0.f;
    float s3a = 0.f, s3b = 0.f, s4a = 0.f, s4b = 0.f, s5a = 0.f, s5b = 0.f;

    #pragma unroll 1
    for (int it = 0; it < 8; it += 4) {
        __syncthreads();   // staged writes visible
        if (it + 4 < 8) {  // issue next phase's loads; drain at post-compute barrier
            #pragma unroll
            for (int p = 0; p < 4; ++p) {
                int dd = d0 - 1 + p;
                bool ok = (dd >= 0) && (dd < DD);
                #pragma unroll
                for (int cc = 0; cc < 4; ++cc)
                    r[cc * 4 + p] = ok ? xb[(size_t)(it + 4 + cc) * NN + dd * NHW + tid] : 0.f;
            }
        }

        for (int cc = 0; cc < 4; ++cc) {
            int cil = it + cc;
            const float* wl0 = wlds + (0 * 8 + cil) * 27;
            const float* wl1 = wlds + (1 * 8 + cil) * 27;
            const float* wl2 = wlds + (2 * 8 + cil) * 27;
            const float* wl3 = wlds + (3 * 8 + cil) * 27;
            const float* wl4 = wlds + (4 * 8 + cil) * 27;
            const float* wl5 = wlds + (5 * 8 + cil) * 27;
            const float* xp  = xl + cc * 4 * XPLANE + rb;
            #pragma unroll
            for (int kh = 0; kh < 3; ++kh) {
                #pragma unroll
                for (int kw = 0; kw < 3; ++kw) {
                    int o = kh * 18 + kw;
                    float x0 = xp[o];
                    float x1 = xp[XPLANE + o];
                    float x2 = xp[2 * XPLANE + o];
                    float x3 = xp[3 * XPLANE + o];
                    #define TAP(KD, XA, XB) { \
                        int t = KD * 9 + kh * 3 + kw; \
                        float w0v = wl0[t], w1v = wl1[t], w2v = wl2[t]; \
                        float w3v = wl3[t], w4v = wl4[t], w5v = wl5[t]; \
                        s0a = fmaf(XA, w0v, s0a); s0b = fmaf(XB, w0v, s0b); \
                        s1a = fmaf(XA, w1v, s1a); s1b = fmaf(XB, w1v, s1b); \
                        s2a = fmaf(XA, w2v, s2a); s2b = fmaf(XB, w2v, s2b); \
                        s3a = fmaf(XA, w3v, s3a); s3b = fmaf(XB, w3v, s3b); \
                        s4a = fmaf(XA, w4v, s4a); s4b = fmaf(XB, w4v, s4b); \
                        s5a = fmaf(XA, w5v, s5a); s5b = fmaf(XB, w5v, s5b); }
                    TAP(0, x0, x1)
                    TAP(1, x1, x2)
                    TAP(2, x2, x3)
                    #undef TAP
                }
            }
        }

        __syncthreads();
        if (it + 4 < 8) {
            #pragma unroll
            for (int j = 0; j < 16; ++j)
                xl[j * XPLANE + wr] = r[j];
        }
    }

    size_t oA = ((size_t)b * CQ + co0) * NN + d0 * NHW + tid;
    unsafeAtomicAdd(&kout[oA],            s0a);
    unsafeAtomicAdd(&kout[oA + NHW],      s0b);
    unsafeAtomicAdd(&kout[oA + NN],       s1a);
    unsafeAtomicAdd(&kout[oA + NN + NHW], s1b);
    unsafeAtomicAdd(&qout[oA],            s2a);
    unsafeAtomicAdd(&qout[oA + NHW],      s2b);
    unsafeAtomicAdd(&qout[oA + NN],       s3a);
    unsafeAtomicAdd(&qout[oA + NN + NHW], s3b);
    unsafeAtomicAdd(&vout[oA],            s4a);
    unsafeAtomicAdd(&vout[oA + NHW],      s4b);
    unsafeAtomicAdd(&vout[oA + NN],       s5a);
    unsafeAtomicAdd(&vout[oA + NN + NHW], s5b);
}

// ---- partial softmax column stats: grid 32c*4mtile*8nchunk = 1024 blocks ----
// Each thread owns 2 m (k in regs), streams a 256-n q chunk from LDS (broadcast
// reads). q pre-scaled by log2e; native exp2. pmax/psum: [c][nchunk][m] (32*8*2048)
__global__ __launch_bounds__(256) void mz_partial_kernel(
    const float* __restrict__ kbuf, const float* __restrict__ qbuf,
    float* __restrict__ pmax, float* __restrict__ psum)
{
    int bid = blockIdx.x;
    int nchunk = bid & 7;
    int mtile  = (bid >> 3) & 3;
    int c      = bid >> 5;

    __shared__ float q0l[256], q1l[256];
    int tid = threadIdx.x;
    int n0 = nchunk * 256;
    if (tid < 64) {
        float4 v = ((const float4*)(qbuf + (size_t)c * NN + n0))[tid];
        v.x *= LOG2E; v.y *= LOG2E; v.z *= LOG2E; v.w *= LOG2E;
        ((float4*)q0l)[tid] = v;
    } else if (tid < 128) {
        float4 v = ((const float4*)(qbuf + (size_t)(CQ + c) * NN + n0))[tid - 64];
        v.x *= LOG2E; v.y *= LOG2E; v.z *= LOG2E; v.w *= LOG2E;
        ((float4*)q1l)[tid - 64] = v;
    }
    __syncthreads();

    int m = mtile * 512 + tid * 2;
    float2 k0 = *(const float2*)(kbuf + (size_t)c * NN + m);
    float2 k1 = *(const float2*)(kbuf + (size_t)(CQ + c) * NN + m);

    const float4* q0v = (const float4*)q0l;
    const float4* q1v = (const float4*)q1l;

    float mxa = -1e30f, mxb = -1e30f;
    #pragma unroll 4
    for (int i = 0; i < 64; ++i) {
        float4 a = q0v[i], b4 = q1v[i];
        float sa0 = fmaf(k0.x, a.x, k1.x * b4.x);
        float sa1 = fmaf(k0.x, a.y, k1.x * b4.y);
        float sa2 = fmaf(k0.x, a.z, k1.x * b4.z);
        float sa3 = fmaf(k0.x, a.w, k1.x * b4.w);
        mxa = fmaxf(mxa, fmaxf(fmaxf(sa0, sa1), fmaxf(sa2, sa3)));
        float sb0 = fmaf(k0.y, a.x, k1.y * b4.x);
        float sb1 = fmaf(k0.y, a.y, k1.y * b4.y);
        float sb2 = fmaf(k0.y, a.z, k1.y * b4.z);
        float sb3 = fmaf(k0.y, a.w, k1.y * b4.w);
        mxb = fmaxf(mxb, fmaxf(fmaxf(sb0, sb1), fmaxf(sb2, sb3)));
    }

    float nma = -mxa, nmb = -mxb;
    float za = 0.f, zb = 0.f;
    #pragma unroll 4
    for (int i = 0; i < 64; ++i) {
        float4 a = q0v[i], b4 = q1v[i];
        za += fast_exp2(fmaf(k0.x, a.x, fmaf(k1.x, b4.x, nma)))
            + fast_exp2(fmaf(k0.x, a.y, fmaf(k1.x, b4.y, nma)))
            + fast_exp2(fmaf(k0.x, a.z, fmaf(k1.x, b4.z, nma)))
            + fast_exp2(fmaf(k0.x, a.w, fmaf(k1.x, b4.w, nma)));
        zb += fast_exp2(fmaf(k0.y, a.x, fmaf(k1.y, b4.x, nmb)))
            + fast_exp2(fmaf(k0.y, a.y, fmaf(k1.y, b4.y, nmb)))
            + fast_exp2(fmaf(k0.y, a.z, fmaf(k1.y, b4.z, nmb)))
            + fast_exp2(fmaf(k0.y, a.w, fmaf(k1.y, b4.w, nmb)));
    }
    size_t o = ((size_t)c * NPART + nchunk) * NN + m;
    float2 rm; rm.x = mxa; rm.y = mxb;
    float2 rz; rz.x = za;  rz.y = zb;
    *(float2*)(pmax + o) = rm;
    *(float2*)(psum + o) = rz;
}

// ---- attention apply partial: grid 32c*4ntile*8mchunk = 1024 blocks ----
// Each thread owns 2 n (pre-scaled q in regs); 256-m chunk of k/vz/negM in LDS,
// every read feeds 2 n. Full 256-thread preamble. parts: 8 x [c][n][b]
__global__ __launch_bounds__(256) void att_partial_kernel(
    const float* __restrict__ kbuf, const float* __restrict__ qbuf,
    const float* __restrict__ vbuf,
    const float* __restrict__ pmax, const float* __restrict__ psum,
    float* __restrict__ parts)
{
    int bid = blockIdx.x;
    int mchunk = bid & 7;
    int ntile  = (bid >> 3) & 3;
    int c      = bid >> 5;

    __shared__ float k0l[256], k1l[256], vz0l[256], vz1l[256], nMl[256];
    int tid = threadIdx.x;
    {
        int m = mchunk * 256 + tid;
        float pj[NPART];
        float M = -1e30f;
        #pragma unroll
        for (int j = 0; j < NPART; ++j) {
            pj[j] = pmax[((size_t)c * NPART + j) * NN + m];
            M = fmaxf(M, pj[j]);
        }
        float z = 0.f;
        #pragma unroll
        for (int j = 0; j < NPART; ++j)
            z += psum[((size_t)c * NPART + j) * NN + m] * fast_exp2(pj[j] - M);
        float rz = 1.f / z;   // z >= 1 always
        k0l[tid]  = kbuf[(size_t)c * NN + m];
        k1l[tid]  = kbuf[(size_t)(CQ + c) * NN + m];
        vz0l[tid] = vbuf[(size_t)c * NN + m] * rz;
        vz1l[tid] = vbuf[(size_t)(CQ + c) * NN + m] * rz;
        nMl[tid]  = -M;
    }
    __syncthreads();

    int n = ntile * 512 + tid * 2;
    float2 q0 = *(const float2*)(qbuf + (size_t)c * NN + n);
    float2 q1 = *(const float2*)(qbuf + (size_t)(CQ + c) * NN + n);
    q0.x *= LOG2E; q0.y *= LOG2E;
    q1.x *= LOG2E; q1.y *= LOG2E;

    const float4* k0v = (const float4*)k0l;
    const float4* k1v = (const float4*)k1l;
    const float4* v0v = (const float4*)vz0l;
    const float4* v1v = (const float4*)vz1l;
    const float4* nMv = (const float4*)nMl;

    float a00 = 0.f, a01 = 0.f;   // b=0: n, n+1
    float a10 = 0.f, a11 = 0.f;   // b=1

    #pragma unroll 2
    for (int i = 0; i < 64; ++i) {
        float4 kk0 = k0v[i], kk1 = k1v[i], w0 = v0v[i], w1 = v1v[i], nm = nMv[i];
        #define ATTS(KX,K1X,W0X,W1X,NMX) { \
            float e0 = fast_exp2(fmaf(q0.x, KX, fmaf(q1.x, K1X, NMX))); \
            float e1 = fast_exp2(fmaf(q0.y, KX, fmaf(q1.y, K1X, NMX))); \
            a00 = fmaf(e0, W0X, a00); a10 = fmaf(e0, W1X, a10); \
            a01 = fmaf(e1, W0X, a01); a11 = fmaf(e1, W1X, a11); }
        ATTS(kk0.x, kk1.x, w0.x, w1.x, nm.x)
        ATTS(kk0.y, kk1.y, w0.y, w1.y, nm.y)
        ATTS(kk0.z, kk1.z, w0.z, w1.z, nm.z)
        ATTS(kk0.w, kk1.w, w0.w, w1.w, nm.w)
        #undef ATTS
    }

    float* dst = parts + (size_t)mchunk * (CQ * NN * BB);
    size_t base = ((size_t)c * NN + n) * BB;
    float4 r0; r0.x = a00; r0.y = a10; r0.z = a01; r0.w = a11;
    *(float4*)(dst + base) = r0;
}

// ---- sum 8 partials -> ybuf: grid 128 blocks ----
__global__ __launch_bounds__(256) void combine_kernel(
    const float* __restrict__ parts, float* __restrict__ ybuf)
{
    int i = blockIdx.x * 256 + threadIdx.x;   // float4 index, 32768 total
    float4 s = ((const float4*)parts)[i];
    #pragma unroll
    for (int j = 1; j < NPART; ++j) {
        float4 p = ((const float4*)(parts + (size_t)j * (CQ * NN * BB)))[i];
        s.x += p.x; s.y += p.y; s.z += p.z; s.w += p.w;
    }
    ((float4*)ybuf)[i] = s;
}

// ---- final conv (32->64): grid 2b*8d*16cog*4cisplit = 1024 blocks ----
__global__ __launch_bounds__(256, 4) void conv_out_kernel(
    const float* __restrict__ ybuf,
    const float* __restrict__ wa,
    float* __restrict__ out)
{
    int bid   = blockIdx.x;
    int split = bid & 3;
    int cog   = (bid >> 2) & 15;
    int d     = (bid >> 6) & 7;
    int b     = bid >> 9;
    int co0   = cog << 2;
    int ci0   = split << 3;   // 8 ci per split

    __shared__ float yl[CI_OUT * 3 * XPLANE];   // 31104 B

    int tid = threadIdx.x;
    int h  = tid >> 4;
    int w  = tid & 15;
    int wr = (h + 1) * 18 + (w + 1);
    int rb = h * 18 + w;

    const float* yb = ybuf + ((size_t)b * CQ + ci0) * NN;

    float r[CI_OUT * 3];
    #pragma unroll
    for (int kd = 0; kd < 3; ++kd) {
        int dd = d + kd - 1;
        bool ok = (dd >= 0) && (dd < DD);
        #pragma unroll
        for (int cc = 0; cc < CI_OUT; ++cc)
            r[cc * 3 + kd] = ok ? yb[(size_t)cc * NN + dd * NHW + tid] : 0.f;
    }
    for (int i = tid; i < CI_OUT * 3 * XPLANE; i += 256) yl[i] = 0.f;
    __syncthreads();
    #pragma unroll
    for (int j = 0; j < CI_OUT * 3; ++j)
        yl[j * XPLANE + wr] = r[j];
    __syncthreads();

    float a0 = 0.f, a1 = 0.f, a2 = 0.f, a3 = 0.f;

    for (int cc = 0; cc < CI_OUT; ++cc) {
        int ci = ci0 + cc;
        const float* w0 = wa + ((size_t)(co0 + 0) * CQ + ci) * 27;
        const float* w1 = wa + ((size_t)(co0 + 1) * CQ + ci) * 27;
        const float* w2 = wa + ((size_t)(co0 + 2) * CQ + ci) * 27;
        const float* w3 = wa + ((size_t)(co0 + 3) * CQ + ci) * 27;
        const float* yp = yl + cc * 3 * XPLANE + rb;
        #pragma unroll
        for (int kd = 0; kd < 3; ++kd) {
            int dd = d + kd - 1;
            if (dd < 0 || dd >= DD) continue;   // block-uniform
            #pragma unroll
            for (int kh = 0; kh < 3; ++kh) {
                #pragma unroll
                for (int kw = 0; kw < 3; ++kw) {
                    float yv = yp[kd * XPLANE + kh * 18 + kw];
                    int t = kd * 9 + kh * 3 + kw;
                    a0 = fmaf(yv, w0[t], a0);
                    a1 = fmaf(yv, w1[t], a1);
                    a2 = fmaf(yv, w2[t], a2);
                    a3 = fmaf(yv, w3[t], a3);
                }
            }
        }
    }

    size_t o = ((size_t)b * COUT + co0) * NN + d * NHW + tid;
    unsafeAtomicAdd(&out[o],          a0);
    unsafeAtomicAdd(&out[o + NN],     a1);
    unsafeAtomicAdd(&out[o + 2 * NN], a2);
    unsafeAtomicAdd(&out[o + 3 * NN], a3);
}

extern "C" void kernel_launch(void* const* d_in, const int* in_sizes, int n_in,
                              void* d_out, int out_size, void* d_ws, size_t ws_size,
                              hipStream_t stream) {
    const float* x  = (const float*)d_in[0];
    const float* wk = (const float*)d_in[1];
    const float* bk = (const float*)d_in[2];
    const float* wq = (const float*)d_in[3];
    const float* bq = (const float*)d_in[4];
    const float* wv = (const float*)d_in[5];
    const float* bv = (const float*)d_in[6];
    const float* wa = (const float*)d_in[7];
    const float* ba = (const float*)d_in[8];
    float* out = (float*)d_out;

    float* ws   = (float*)d_ws;
    float* kbuf = ws;                        // [2][32][2048]        131072
    float* qbuf = kbuf + BB * CQ * NN;       // [2][32][2048]        131072
    float* vbuf = qbuf + BB * CQ * NN;       // [2][32][2048]        131072
    float* pmax = vbuf + BB * CQ * NN;       // [32][8][2048]        524288
    float* psum = pmax + CQ * NPART * NN;    // [32][8][2048]        524288
    float* parts = psum + CQ * NPART * NN;   // 8 x [32][2048][2]    1048576
    float* ybuf = kbuf;                      // alias: kbuf dead after att

    init_kernel<<<1536, 256, 0, stream>>>(bk, bq, bv, ba, x, kbuf, qbuf, vbuf, out);
    conv_qkv_kernel<<<1024, 256, 0, stream>>>(x, wk, wq, wv, kbuf, qbuf, vbuf);
    mz_partial_kernel<<<1024, 256, 0, stream>>>(kbuf, qbuf, pmax, psum);
    att_partial_kernel<<<1024, 256, 0, stream>>>(kbuf, qbuf, vbuf, pmax, psum, parts);
    combine_kernel<<<128, 256, 0, stream>>>(parts, ybuf);
    conv_out_kernel<<<1024, 256, 0, stream>>>(ybuf, wa, out);
}